// Round 1
// baseline (321.269 us; speedup 1.0000x reference)
//
#include <hip/hip_runtime.h>

// Tensor-ring layer, restructured:
//   A  = g01[ij][ac][pq] = sum_b f0[i,a,b,p] f1[j,b,c,q]          (1 MB)
//   B  = g23[kl][ac][st] = sum_d f2[k,c,d,s] f3[l,d,a,t]          (1 MB)
//   T4[ijkl][o] = sum_{ac,pq,st} A[ij][ac][pq] B[kl][ac][st] core[pq,st,o]
//   Y  = x @ T4      (4096x4096 * 4096x64)
//   out= Y @ out_factor + bias
// ws layout (floats): A 0..262144, B ..524288, T4 ..786432, Y ..1048576 (4 MB)

__global__ __launch_bounds__(256) void k_g01(const float* __restrict__ f0,
                                             const float* __restrict__ f1,
                                             float* __restrict__ A) {
  int ij = blockIdx.x;                    // 64 blocks
  int i = ij >> 3, j = ij & 7;
  __shared__ float lf0[512], lf1[512];
  int tid = threadIdx.x;
  if (tid < 128)
    reinterpret_cast<float4*>(lf0)[tid] = reinterpret_cast<const float4*>(f0 + i * 512)[tid];
  else
    reinterpret_cast<float4*>(lf1)[tid - 128] = reinterpret_cast<const float4*>(f1 + j * 512)[tid - 128];
  __syncthreads();
#pragma unroll
  for (int r = 0; r < 16; ++r) {
    int idx = r * 256 + tid;              // coalesced
    int ac = idx >> 6, pq = idx & 63;
    int a = ac >> 3, c = ac & 7, p = pq >> 3, q = pq & 7;
    float acc = 0.f;
#pragma unroll
    for (int b = 0; b < 8; ++b)
      acc = fmaf(lf0[a * 64 + b * 8 + p], lf1[b * 64 + c * 8 + q], acc);
    A[ij * 4096 + idx] = acc;
  }
}

__global__ __launch_bounds__(256) void k_g23(const float* __restrict__ f2,
                                             const float* __restrict__ f3,
                                             float* __restrict__ B) {
  int kl = blockIdx.x;                    // 64 blocks
  int k = kl >> 3, l = kl & 7;
  __shared__ float lf2[512], lf3[512];
  int tid = threadIdx.x;
  if (tid < 128)
    reinterpret_cast<float4*>(lf2)[tid] = reinterpret_cast<const float4*>(f2 + k * 512)[tid];
  else
    reinterpret_cast<float4*>(lf3)[tid - 128] = reinterpret_cast<const float4*>(f3 + l * 512)[tid - 128];
  __syncthreads();
#pragma unroll
  for (int r = 0; r < 16; ++r) {
    int idx = r * 256 + tid;
    int ac = idx >> 6, st = idx & 63;
    int a = ac >> 3, c = ac & 7, s = st >> 3, t = st & 7;
    float acc = 0.f;
#pragma unroll
    for (int d = 0; d < 8; ++d)
      acc = fmaf(lf2[c * 64 + d * 8 + s], lf3[d * 64 + a * 8 + t], acc);
    B[kl * 4096 + idx] = acc;
  }
}

// One block: one ij, 4 consecutive kl. LDS = lA 16KB + lS 64KB = 80KB -> 2 blocks/CU.
__global__ __launch_bounds__(256) void k_t4(const float* __restrict__ A,
                                            const float* __restrict__ B,
                                            const float* __restrict__ core,
                                            float* __restrict__ T4) {
  int bid = blockIdx.x;                   // 1024
  int ij = bid >> 4, kl0 = (bid & 15) * 4;
  __shared__ float lA[4096];
  __shared__ float lS[4][4096];
  int tid = threadIdx.x;
#pragma unroll
  for (int r = 0; r < 4; ++r)
    reinterpret_cast<float4*>(lA)[r * 256 + tid] =
        reinterpret_cast<const float4*>(A + ij * 4096)[r * 256 + tid];
  __syncthreads();

  int pq0 = (tid >> 4) << 2;              // 0,4,...,60
  int st04 = tid & 15;                    // float4 index over st
#pragma unroll 1
  for (int m = 0; m < 4; ++m) {
    const float4* Bp = reinterpret_cast<const float4*>(B + (kl0 + m) * 4096);
    float acc[4][4] = {{0.f}};
    for (int ac = 0; ac < 64; ++ac) {
      float4 av = reinterpret_cast<float4*>(lA)[ac * 16 + (pq0 >> 2)];
      float4 bv = Bp[ac * 16 + st04];     // L1-hot (16KB per pair)
      float au[4] = {av.x, av.y, av.z, av.w};
      float bu[4] = {bv.x, bv.y, bv.z, bv.w};
#pragma unroll
      for (int u = 0; u < 4; ++u)
#pragma unroll
        for (int v = 0; v < 4; ++v)
          acc[u][v] = fmaf(au[u], bu[v], acc[u][v]);
    }
    float4* S4 = reinterpret_cast<float4*>(lS[m]);
#pragma unroll
    for (int u = 0; u < 4; ++u)
      S4[(pq0 + u) * 16 + st04] = make_float4(acc[u][0], acc[u][1], acc[u][2], acc[u][3]);
  }
  __syncthreads();

  // fold with core: thread = (seg of pqst, 4 consecutive o)
  int o44 = tid & 15, seg = tid >> 4;     // 16 segs x 256 midx
  const float4* c4 = reinterpret_cast<const float4*>(core);
  float4 r0 = {0, 0, 0, 0}, r1 = r0, r2 = r0, r3 = r0;
  for (int n = 0; n < 256; ++n) {
    int midx = seg * 256 + n;
    float4 cv = c4[midx * 16 + o44];      // coalesced 256B/wave, L2-resident
    float s0 = lS[0][midx], s1 = lS[1][midx], s2 = lS[2][midx], s3 = lS[3][midx];
    r0.x = fmaf(s0, cv.x, r0.x); r0.y = fmaf(s0, cv.y, r0.y);
    r0.z = fmaf(s0, cv.z, r0.z); r0.w = fmaf(s0, cv.w, r0.w);
    r1.x = fmaf(s1, cv.x, r1.x); r1.y = fmaf(s1, cv.y, r1.y);
    r1.z = fmaf(s1, cv.z, r1.z); r1.w = fmaf(s1, cv.w, r1.w);
    r2.x = fmaf(s2, cv.x, r2.x); r2.y = fmaf(s2, cv.y, r2.y);
    r2.z = fmaf(s2, cv.z, r2.z); r2.w = fmaf(s2, cv.w, r2.w);
    r3.x = fmaf(s3, cv.x, r3.x); r3.y = fmaf(s3, cv.y, r3.y);
    r3.z = fmaf(s3, cv.z, r3.z); r3.w = fmaf(s3, cv.w, r3.w);
  }
  // reduce 16 segs via lA (done being read; barrier below before reads)
  float4* red = reinterpret_cast<float4*>(lA);
  red[(seg * 4 + 0) * 16 + o44] = r0;
  red[(seg * 4 + 1) * 16 + o44] = r1;
  red[(seg * 4 + 2) * 16 + o44] = r2;
  red[(seg * 4 + 3) * 16 + o44] = r3;
  __syncthreads();
  int m2 = tid >> 6, o = tid & 63;
  float t = 0.f;
#pragma unroll
  for (int s2 = 0; s2 < 16; ++s2) t += lA[(s2 * 4 + m2) * 64 + o];
  T4[(ij * 64 + kl0 + m2) * 64 + o] = t;  // coalesced
}

// Y[b][o] = sum_k x[b][k] * T4[k][o]; block = 16 rows, 256 blocks
__global__ __launch_bounds__(256) void k_y(const float* __restrict__ x,
                                           const float* __restrict__ T4,
                                           float* __restrict__ Y) {
  int b0 = blockIdx.x * 16;
  __shared__ float lx[1024];              // [16 rows][64 k]
  int tid = threadIdx.x;
  int o = tid & 63, rg = tid >> 6;        // rows rg*4 .. rg*4+3
  float acc0 = 0.f, acc1 = 0.f, acc2 = 0.f, acc3 = 0.f;
  const float4* lx4 = reinterpret_cast<const float4*>(lx);
  for (int kc = 0; kc < 4096; kc += 64) {
    __syncthreads();
    reinterpret_cast<float4*>(lx)[tid] =
        *reinterpret_cast<const float4*>(x + (b0 + (tid >> 4)) * 4096 + kc + (tid & 15) * 4);
    __syncthreads();
#pragma unroll 4
    for (int kk = 0; kk < 64; kk += 4) {
      float c0 = T4[(kc + kk + 0) * 64 + o];   // 256B/wave, L1-hot
      float c1 = T4[(kc + kk + 1) * 64 + o];
      float c2 = T4[(kc + kk + 2) * 64 + o];
      float c3 = T4[(kc + kk + 3) * 64 + o];
      float4 xv;
      xv = lx4[(rg * 4 + 0) * 16 + (kk >> 2)];
      acc0 = fmaf(xv.x, c0, fmaf(xv.y, c1, fmaf(xv.z, c2, fmaf(xv.w, c3, acc0))));
      xv = lx4[(rg * 4 + 1) * 16 + (kk >> 2)];
      acc1 = fmaf(xv.x, c0, fmaf(xv.y, c1, fmaf(xv.z, c2, fmaf(xv.w, c3, acc1))));
      xv = lx4[(rg * 4 + 2) * 16 + (kk >> 2)];
      acc2 = fmaf(xv.x, c0, fmaf(xv.y, c1, fmaf(xv.z, c2, fmaf(xv.w, c3, acc2))));
      xv = lx4[(rg * 4 + 3) * 16 + (kk >> 2)];
      acc3 = fmaf(xv.x, c0, fmaf(xv.y, c1, fmaf(xv.z, c2, fmaf(xv.w, c3, acc3))));
    }
  }
  Y[(b0 + rg * 4 + 0) * 64 + o] = acc0;
  Y[(b0 + rg * 4 + 1) * 64 + o] = acc1;
  Y[(b0 + rg * 4 + 2) * 64 + o] = acc2;
  Y[(b0 + rg * 4 + 3) * 64 + o] = acc3;
}

// out[b][f] = sum_o Y[b][o] * OF[o][f] + bias[f]; block = 16 rows x 1024 f
__global__ __launch_bounds__(256) void k_out(const float* __restrict__ Y,
                                             const float* __restrict__ OF_,
                                             const float* __restrict__ bias,
                                             float* __restrict__ out) {
  int b0 = blockIdx.x * 16;               // 256 blocks
  int tid = threadIdx.x;                  // f4 = tid -> f = tid*4
  __shared__ float lY[1024];              // [16 rows][64 o]
  reinterpret_cast<float4*>(lY)[tid] =
      *reinterpret_cast<const float4*>(Y + (b0 + (tid >> 4)) * 64 + (tid & 15) * 4);
  __syncthreads();
  float4 acc[16];
#pragma unroll
  for (int r = 0; r < 16; ++r) acc[r] = make_float4(0.f, 0.f, 0.f, 0.f);
  for (int oo = 0; oo < 64; ++oo) {
    float4 w = *reinterpret_cast<const float4*>(OF_ + oo * 1024 + tid * 4);
#pragma unroll
    for (int r = 0; r < 16; ++r) {
      float yv = lY[r * 64 + oo];         // uniform -> LDS broadcast
      acc[r].x = fmaf(yv, w.x, acc[r].x);
      acc[r].y = fmaf(yv, w.y, acc[r].y);
      acc[r].z = fmaf(yv, w.z, acc[r].z);
      acc[r].w = fmaf(yv, w.w, acc[r].w);
    }
  }
  float4 bv = *reinterpret_cast<const float4*>(bias + tid * 4);
#pragma unroll
  for (int r = 0; r < 16; ++r) {
    float4 v = acc[r];
    v.x += bv.x; v.y += bv.y; v.z += bv.z; v.w += bv.w;
    *reinterpret_cast<float4*>(out + (b0 + r) * 1024 + tid * 4) = v;
  }
}

extern "C" void kernel_launch(void* const* d_in, const int* in_sizes, int n_in,
                              void* d_out, int out_size, void* d_ws, size_t ws_size,
                              hipStream_t stream) {
  const float* x    = (const float*)d_in[0];
  const float* f0   = (const float*)d_in[1];
  const float* f1   = (const float*)d_in[2];
  const float* f2   = (const float*)d_in[3];
  const float* f3   = (const float*)d_in[4];
  const float* core = (const float*)d_in[5];
  const float* ofac = (const float*)d_in[6];
  const float* bias = (const float*)d_in[7];
  float* out = (float*)d_out;

  float* A  = (float*)d_ws;               // 262144 floats
  float* B  = A + 262144;
  float* T4 = B + 262144;
  float* Yb = T4 + 262144;

  k_g01<<<64, 256, 0, stream>>>(f0, f1, A);
  k_g23<<<64, 256, 0, stream>>>(f2, f3, B);
  k_t4<<<1024, 256, 0, stream>>>(A, B, core, T4);
  k_y<<<256, 256, 0, stream>>>(x, T4, Yb);
  k_out<<<256, 256, 0, stream>>>(Yb, ofac, bias, out);
}